// Round 8
// baseline (121.738 us; speedup 1.0000x reference)
//
#include <hip/hip_runtime.h>
#include <hip/hip_bf16.h>

// B=512, T=256, C=384, H=64 single-head causal attention.
// Round 7: persistent 256-block fused kernel, cross-generation prefetch.
//   prep_bt: W -> Bt[192][384] bf16 in ws.
//   fused  : grid 256 (block = CU), 512 threads (8 waves); each block runs
//            batches {bid, bid+256} back to back.
//     Per gen: stage Bt [192][392] LDS (150.5 KB) -> GEMM (wave w: rows
//       [32w,32w+32) x 192; A from global via 4-deep reg ring pA..pD, no
//       barriers in K-loop) -> epilogue to LDS overlay (q swz / kl swz /
//       vt swz) -> attn (strips {16w,240-16w}, 5 tiles/wave).
//     Gen-2's first 4 chunks are issued BEFORE gen-1's attn phase, and
//     gen-1's before Bt staging: HBM never idles across phase boundaries.

constexpr int BSZ  = 512;
constexpr int TT   = 256;
constexpr int CDIM = 384;
constexpr int HDIM = 64;
constexpr int NQKV = 192;
constexpr float SCALE = 0.051031036307982884f;  // 384^-0.5 (C, not head size)
constexpr int BTST = 392;   // Bt LDS row stride (784 B)

typedef __attribute__((ext_vector_type(8))) short bf16x8;
typedef __attribute__((ext_vector_type(4))) float f32x4;

__device__ inline unsigned short f2bf(float f) {
    __hip_bfloat16 h = __float2bfloat16(f);
    return *(unsigned short*)&h;
}
__device__ inline bf16x8 pack8(float4 a, float4 b) {
    unsigned short p[8] = { f2bf(a.x), f2bf(a.y), f2bf(a.z), f2bf(a.w),
                            f2bf(b.x), f2bf(b.y), f2bf(b.z), f2bf(b.w) };
    return *(bf16x8*)p;
}

// ---------------- kernel 0: Bt[192][384] bf16 = [Wq|Wk|Wv]^T ----------------
__global__ __launch_bounds__(256) void prep_bt(
    const float* __restrict__ Wq, const float* __restrict__ Wk,
    const float* __restrict__ Wv, unsigned short* __restrict__ bt)
{
    int idx = blockIdx.x * 256 + threadIdx.x;
    if (idx >= NQKV * CDIM) return;
    int n = idx / CDIM, k = idx - n * CDIM;
    const float* W = (n < 64) ? Wq : (n < 128) ? Wk : Wv;
    bt[idx] = f2bf(W[(size_t)k * HDIM + (n & 63)]);
}

// ---------------- persistent fused QKV-projection + flash attention ----------------
__global__ __launch_bounds__(512, 2) void fused(
    const float* __restrict__ x, const unsigned short* __restrict__ bt,
    float* __restrict__ out)
{
    // GEMM phase: smem = Bt [192][392] (150,528 B)
    // attn phase overlay: qs[256][64] (q, then P) | kl[256][64] | vt[64][256]
    __shared__ __align__(16) unsigned short smem[NQKV * BTST];
    unsigned short* btl = smem;
    unsigned short* qs  = smem;
    unsigned short* kl  = smem + 16384;
    unsigned short* vt  = smem + 32768;

    const int tid = threadIdx.x;
    const int w = tid >> 6, lane = tid & 63;
    const int lr = lane & 15, lk = lane >> 4;
    const int m0 = 32 * w;

    const float* xr0 = x + ((size_t)blockIdx.x * TT + m0 + lr) * CDIM + lk * 8;
    const float* xr1 = xr0 + 16 * CDIM;

    float4 pA[4], pB[4], pC[4], pD[4];
#define LDCH(P, ks) { \
    P[0] = *(const float4*)&xr0[(ks) * 32];     \
    P[1] = *(const float4*)&xr0[(ks) * 32 + 4]; \
    P[2] = *(const float4*)&xr1[(ks) * 32];     \
    P[3] = *(const float4*)&xr1[(ks) * 32 + 4]; }
#define STEP(P, ks, cond) { \
    bf16x8 a0 = pack8(P[0], P[1]); \
    bf16x8 a1 = pack8(P[2], P[3]); \
    if (cond) LDCH(P, (ks) + 4); \
    _Pragma("unroll") \
    for (int ni = 0; ni < 12; ++ni) { \
        bf16x8 bb2 = *(const bf16x8*)&btl[(ni * 16 + lr) * BTST + (ks) * 32 + lk * 8]; \
        acc0[ni] = __builtin_amdgcn_mfma_f32_16x16x32_bf16(a0, bb2, acc0[ni], 0, 0, 0); \
        acc1[ni] = __builtin_amdgcn_mfma_f32_16x16x32_bf16(a1, bb2, acc1[ni], 0, 0, 0); \
    } }

    // prefetch gen-0 chunks 0..3 (hides under Bt staging)
    LDCH(pA, 0) LDCH(pB, 1) LDCH(pC, 2) LDCH(pD, 3)

    for (int g = 0; g < 2; ++g) {
        const int bcur = blockIdx.x + g * 256;

        // ---- stage Bt into LDS: 9216 uint4, 18 per thread ----
        #pragma unroll
        for (int p = 0; p < 18; ++p) {
            int i = p * 512 + tid;
            int row = i / 48, c8 = i - row * 48;
            *(uint4*)&btl[row * BTST + c8 * 8] = ((const uint4*)bt)[i];
        }
        __syncthreads();

        // ---- GEMM: wave w -> rows [32w,32w+32) x 192, K = 384 ----
        f32x4 acc0[12], acc1[12];
        #pragma unroll
        for (int ni = 0; ni < 12; ++ni) {
            acc0[ni] = (f32x4){0.f, 0.f, 0.f, 0.f};
            acc1[ni] = (f32x4){0.f, 0.f, 0.f, 0.f};
        }
        #pragma unroll
        for (int kk = 0; kk < 3; ++kk) {
            STEP(pA, 4 * kk + 0, kk < 2)
            STEP(pB, 4 * kk + 1, kk < 2)
            STEP(pC, 4 * kk + 2, kk < 2)
            STEP(pD, 4 * kk + 3, kk < 2)
        }
        __syncthreads();   // all Bt reads done before overlay writes

        // ---- epilogue: D-frags -> LDS homes. col=ni*16+lr, row=m0+mi*16+lk*4+r
        #pragma unroll
        for (int mi = 0; mi < 2; ++mi) {
            const f32x4* am = mi ? acc1 : acc0;
            #pragma unroll
            for (int ni = 0; ni < 4; ++ni)          // q: cols 0..63, pre-scaled
                #pragma unroll
                for (int r = 0; r < 4; ++r) {
                    int row = m0 + mi * 16 + lk * 4 + r;
                    int h   = ni * 16 + lr;
                    qs[row * 64 + (h ^ ((row & 7) << 3))] = f2bf(am[ni][r] * SCALE);
                }
            #pragma unroll
            for (int ni = 4; ni < 8; ++ni)          // k -> kl[t][h] swz
                #pragma unroll
                for (int r = 0; r < 4; ++r) {
                    int row = m0 + mi * 16 + lk * 4 + r;
                    int c2  = (ni - 4) * 16 + lr;
                    kl[row * 64 + (c2 ^ ((row & 7) << 3))] = f2bf(am[ni][r]);
                }
            #pragma unroll
            for (int ni = 8; ni < 12; ++ni) {       // v -> vt[h][t] swz, uint2
                int h  = (ni - 8) * 16 + lr;
                int t0 = m0 + mi * 16 + lk * 4;
                unsigned short pk[4];
                #pragma unroll
                for (int r = 0; r < 4; ++r) pk[r] = f2bf(am[ni][r]);
                *(uint2*)&vt[h * 256 + (t0 ^ ((h & 7) << 3))] = *(uint2*)pk;
            }
        }
        __syncthreads();

        // ---- cross-generation prefetch: keep HBM busy through attn ----
        if (g == 0) {
            xr0 += (size_t)256 * TT * CDIM;
            xr1 += (size_t)256 * TT * CDIM;
            LDCH(pA, 0) LDCH(pB, 1) LDCH(pC, 2) LDCH(pD, 3)
        }

        // ---- attention: wave w owns strips {16w, 240-16w}, 5 tiles ----
        const int q0a[2]   = {16 * w, 240 - 16 * w};
        const int lastA[2] = {(q0a[0] + 15) >> 6, (q0a[1] + 15) >> 6};

        bf16x8 qa[2][2];
        #pragma unroll
        for (int s2 = 0; s2 < 2; ++s2)
            #pragma unroll
            for (int kc = 0; kc < 2; ++kc)
                qa[s2][kc] = *(const bf16x8*)
                    &qs[(q0a[s2] + lr) * 64 + ((kc * 32 + lk * 8) ^ ((lr & 7) << 3))];
        // P region = qs rows [16w,16w+16): own strip-0 Q (same-wave DS order);
        // strip-1 Q rows are >=128, never a P region -> no barrier needed.
        unsigned short* pb = qs + w * 1024;

        f32x4 oacc[2][4];
        float mrow[2][4], lpart[2][4];
        #pragma unroll
        for (int s2 = 0; s2 < 2; ++s2) {
            #pragma unroll
            for (int nh = 0; nh < 4; ++nh) oacc[s2][nh] = (f32x4){0.f, 0.f, 0.f, 0.f};
            #pragma unroll
            for (int r = 0; r < 4; ++r) { mrow[s2][r] = -INFINITY; lpart[s2][r] = 0.f; }
        }

        for (int st = 0; st <= lastA[1]; ++st) {
            #pragma unroll
            for (int s2 = 0; s2 < 2; ++s2) {
                if (st > lastA[s2]) continue;
                const int q0 = q0a[s2];

                f32x4 sa[4];
                #pragma unroll
                for (int ni = 0; ni < 4; ++ni) sa[ni] = (f32x4){0.f, 0.f, 0.f, 0.f};
                #pragma unroll
                for (int ni = 0; ni < 4; ++ni) {
                    int row = st * 64 + ni * 16 + lr;
                    #pragma unroll
                    for (int kc = 0; kc < 2; ++kc) {
                        bf16x8 kb = *(const bf16x8*)
                            &kl[row * 64 + ((kc * 32 + lk * 8) ^ ((lr & 7) << 3))];
                        sa[ni] = __builtin_amdgcn_mfma_f32_16x16x32_bf16(
                            qa[s2][kc], kb, sa[ni], 0, 0, 0);
                    }
                }
                if (st == lastA[s2]) {   // causal mask on diagonal tile
                    #pragma unroll
                    for (int ni = 0; ni < 4; ++ni) {
                        int sg = st * 64 + ni * 16 + lr;
                        #pragma unroll
                        for (int r = 0; r < 4; ++r) {
                            int qg = q0 + lk * 4 + r;
                            if (sg > qg) sa[ni][r] = -INFINITY;
                        }
                    }
                }
                float pm[4];
                #pragma unroll
                for (int r = 0; r < 4; ++r)
                    pm[r] = fmaxf(fmaxf(sa[0][r], sa[1][r]), fmaxf(sa[2][r], sa[3][r]));
                #pragma unroll
                for (int stp = 1; stp < 16; stp <<= 1)
                    #pragma unroll
                    for (int r = 0; r < 4; ++r)
                        pm[r] = fmaxf(pm[r], __shfl_xor(pm[r], stp));
                float mnew[4];
                #pragma unroll
                for (int r = 0; r < 4; ++r) {
                    float mn = fmaxf(mrow[s2][r], pm[r]);
                    float corr = __expf(mrow[s2][r] - mn);   // exp(-inf)=0 first time
                    mrow[s2][r] = mn; mnew[r] = mn;
                    lpart[s2][r] *= corr;
                    #pragma unroll
                    for (int nh = 0; nh < 4; ++nh) oacc[s2][nh][r] *= corr;
                }
                #pragma unroll
                for (int ni = 0; ni < 4; ++ni) {
                    int s = ni * 16 + lr;
                    #pragma unroll
                    for (int r = 0; r < 4; ++r) {
                        float p = __expf(sa[ni][r] - mnew[r]);
                        lpart[s2][r] += p;
                        int qr = lk * 4 + r;
                        pb[qr * 64 + (s ^ ((qr & 7) << 3))] = f2bf(p);
                    }
                }
                bf16x8 pa[2];
                #pragma unroll
                for (int kc = 0; kc < 2; ++kc)
                    pa[kc] = *(const bf16x8*)
                        &pb[lr * 64 + ((kc * 32 + lk * 8) ^ ((lr & 7) << 3))];
                #pragma unroll
                for (int nh = 0; nh < 4; ++nh) {
                    int hrow = nh * 16 + lr;
                    #pragma unroll
                    for (int kc = 0; kc < 2; ++kc) {
                        bf16x8 vb = *(const bf16x8*)
                            &vt[hrow * 256 + ((st * 64 + kc * 32 + lk * 8) ^ ((hrow & 7) << 3))];
                        oacc[s2][nh] = __builtin_amdgcn_mfma_f32_16x16x32_bf16(
                            pa[kc], vb, oacc[s2][nh], 0, 0, 0);
                    }
                }
            }
        }

        // ---- finalize ----
        #pragma unroll
        for (int s2 = 0; s2 < 2; ++s2) {
            float linv[4];
            #pragma unroll
            for (int r = 0; r < 4; ++r) {
                float l = lpart[s2][r];
                #pragma unroll
                for (int stp = 1; stp < 16; stp <<= 1) l += __shfl_xor(l, stp);
                linv[r] = 1.0f / l;
            }
            #pragma unroll
            for (int nh = 0; nh < 4; ++nh)
                #pragma unroll
                for (int r = 0; r < 4; ++r) {
                    size_t row = (size_t)bcur * TT + q0a[s2] + lk * 4 + r;
                    out[row * HDIM + nh * 16 + lr] = oacc[s2][nh][r] * linv[r];
                }
        }

        if (g == 0) __syncthreads();   // attn LDS reads done before Bt restage
    }
#undef LDCH
#undef STEP
}

extern "C" void kernel_launch(void* const* d_in, const int* in_sizes, int n_in,
                              void* d_out, int out_size, void* d_ws, size_t ws_size,
                              hipStream_t stream)
{
    const float* x  = (const float*)d_in[0];
    const float* Wq = (const float*)d_in[1];
    const float* Wk = (const float*)d_in[2];
    const float* Wv = (const float*)d_in[3];
    unsigned short* bt = (unsigned short*)d_ws;   // [192][384] bf16 = 147 KB
    float* out = (float*)d_out;

    prep_bt<<<(NQKV * CDIM + 255) / 256, 256, 0, stream>>>(Wq, Wk, Wv, bt);
    fused<<<BSZ / 2, 512, 0, stream>>>(x, bt, out);
}

// Round 9
// 65.502 us; speedup vs baseline: 1.8586x; 1.8586x over previous
//
#include <hip/hip_runtime.h>
#include <hip/hip_bf16.h>

// B=512, T=256, C=384, H=64 single-head causal attention.
// Round 8: R5 structure (best, 65us) + 3-deep prefetch ring + early issue.
//   prep_bt: W -> Bt[192][384] bf16 in ws.
//   fused  : grid 512 (block = batch), 1024 threads (16 waves), 1 block/CU.
//     Bt staged in LDS [192][392] (150.5 KB, overlaid by attn tiles after).
//     GEMM: wave w owns rows [16w,16w+16) x N=192; A direct global->reg via
//       3-deep ring pA/pB/pC (first 3 chunks issued BEFORE Bt staging; no
//       barriers in K-loop). acc[12] f32x4.
//     Epilogue -> LDS overlay: q (xSCALE) -> wave-private pq swz; K -> kl swz;
//       V -> vt[64][256] swz (uint2).
//     Attn: wave w owns q rows [16w,16w+16), tiles st=0..w>>2 (per-SIMD
//       balanced {1,2,3,4}). P reuses pq. Same math as R5.

constexpr int BSZ  = 512;
constexpr int TT   = 256;
constexpr int CDIM = 384;
constexpr int HDIM = 64;
constexpr int NQKV = 192;
constexpr float SCALE = 0.051031036307982884f;  // 384^-0.5 (C, not head size)
constexpr int BTST = 392;   // Bt LDS row stride (784 B)

typedef __attribute__((ext_vector_type(8))) short bf16x8;
typedef __attribute__((ext_vector_type(4))) float f32x4;

__device__ inline unsigned short f2bf(float f) {
    __hip_bfloat16 h = __float2bfloat16(f);
    return *(unsigned short*)&h;
}
__device__ inline bf16x8 pack8(float4 a, float4 b) {
    unsigned short p[8] = { f2bf(a.x), f2bf(a.y), f2bf(a.z), f2bf(a.w),
                            f2bf(b.x), f2bf(b.y), f2bf(b.z), f2bf(b.w) };
    return *(bf16x8*)p;
}

// ---------------- kernel 0: Bt[192][384] bf16 = [Wq|Wk|Wv]^T ----------------
__global__ __launch_bounds__(256) void prep_bt(
    const float* __restrict__ Wq, const float* __restrict__ Wk,
    const float* __restrict__ Wv, unsigned short* __restrict__ bt)
{
    int idx = blockIdx.x * 256 + threadIdx.x;
    if (idx >= NQKV * CDIM) return;
    int n = idx / CDIM, k = idx - n * CDIM;
    const float* W = (n < 64) ? Wq : (n < 128) ? Wk : Wv;
    bt[idx] = f2bf(W[(size_t)k * HDIM + (n & 63)]);
}

// ---------------- fused QKV-projection + flash attention ----------------
__global__ __launch_bounds__(1024) void fused(
    const float* __restrict__ x, const unsigned short* __restrict__ bt,
    float* __restrict__ out)
{
    // GEMM phase: smem = Bt [192][392] (150,528 B)
    // attn phase overlay: qs[256][64] (q, then P) | kl[256][64] | vt[64][256]
    __shared__ __align__(16) unsigned short smem[NQKV * BTST];
    unsigned short* btl = smem;
    unsigned short* qs  = smem;
    unsigned short* kl  = smem + 16384;
    unsigned short* vt  = smem + 32768;

    const int b = blockIdx.x, tid = threadIdx.x;
    const int w = tid >> 6, lane = tid & 63;
    const int lr = lane & 15, lk = lane >> 4;

    // ---- GEMM: wave w -> rows [16w,16w+16) x 192, K = 384 ----
    const float* xr0 = x + ((size_t)b * TT + 16 * w + lr) * CDIM + lk * 8;

    float4 pA[2], pB[2], pC[2];
#define LDCH(P, ks) { \
    P[0] = *(const float4*)&xr0[(ks) * 32];     \
    P[1] = *(const float4*)&xr0[(ks) * 32 + 4]; }
#define STEP(P, ks, cond) { \
    bf16x8 a = pack8(P[0], P[1]); \
    if (cond) LDCH(P, (ks) + 3); \
    _Pragma("unroll") \
    for (int ni = 0; ni < 12; ++ni) { \
        bf16x8 bb = *(const bf16x8*)&btl[(ni * 16 + lr) * BTST + (ks) * 32 + lk * 8]; \
        acc[ni] = __builtin_amdgcn_mfma_f32_16x16x32_bf16(a, bb, acc[ni], 0, 0, 0); \
    } }

    // issue chunks 0..2 before Bt staging: memory pipe busy from cycle 0
    LDCH(pA, 0) LDCH(pB, 1) LDCH(pC, 2)

    // ---- stage Bt into LDS: 9216 uint4, 9 per thread, coalesced ----
    #pragma unroll
    for (int p = 0; p < 9; ++p) {
        int i = p * 1024 + tid;
        int row = i / 48, c8 = i - row * 48;
        *(uint4*)&btl[row * BTST + c8 * 8] = ((const uint4*)bt)[i];
    }
    __syncthreads();

    f32x4 acc[12];
    #pragma unroll
    for (int ni = 0; ni < 12; ++ni) acc[ni] = (f32x4){0.f, 0.f, 0.f, 0.f};

    #pragma unroll
    for (int kk = 0; kk < 4; ++kk) {
        STEP(pA, 3 * kk + 0, kk < 3)
        STEP(pB, 3 * kk + 1, kk < 3)
        STEP(pC, 3 * kk + 2, kk < 3)
    }
#undef LDCH
#undef STEP
    __syncthreads();   // all Bt reads done before overlay writes

    // ---- epilogue: D-frags -> LDS homes. D: col=ni*16+lr, rowIn16=lk*4+r ----
    unsigned short* pq = qs + w * 1024;   // wave-private 16x64 (q, then P)
    #pragma unroll
    for (int ni = 0; ni < 4; ++ni)        // q: cols 0..63, pre-scaled
        #pragma unroll
        for (int r = 0; r < 4; ++r) {
            int qr = lk * 4 + r;
            int h  = ni * 16 + lr;
            pq[qr * 64 + (h ^ ((qr & 7) << 3))] = f2bf(acc[ni][r] * SCALE);
        }
    #pragma unroll
    for (int ni = 4; ni < 8; ++ni)        // k: cols 64..127 -> kl[t][h] swz
        #pragma unroll
        for (int r = 0; r < 4; ++r) {
            int row = 16 * w + lk * 4 + r;
            int c2  = (ni - 4) * 16 + lr;
            kl[row * 64 + (c2 ^ ((row & 7) << 3))] = f2bf(acc[ni][r]);
        }
    #pragma unroll
    for (int ni = 8; ni < 12; ++ni) {     // v: cols 128..191 -> vt[h][t] swz
        int h  = (ni - 8) * 16 + lr;
        int t0 = 16 * w + lk * 4;
        unsigned short pk[4];
        #pragma unroll
        for (int r = 0; r < 4; ++r) pk[r] = f2bf(acc[ni][r]);
        *(uint2*)&vt[h * 256 + (t0 ^ ((h & 7) << 3))] = *(uint2*)pk;
    }
    __syncthreads();

    // ---- attention: wave w owns q-rows [16w,16w+16) ----
    const int q0 = 16 * w;
    bf16x8 qa[2];
    #pragma unroll
    for (int kc = 0; kc < 2; ++kc)
        qa[kc] = *(const bf16x8*)&pq[lr * 64 + ((kc * 32 + lk * 8) ^ ((lr & 7) << 3))];
    // (qa read precedes P writes to same region — same wave, DS in-order)

    f32x4 oacc[4];
    float mrow[4], lpart[4];
    #pragma unroll
    for (int nh = 0; nh < 4; ++nh) oacc[nh] = (f32x4){0.f, 0.f, 0.f, 0.f};
    #pragma unroll
    for (int r = 0; r < 4; ++r) { mrow[r] = -INFINITY; lpart[r] = 0.f; }

    const int lastt = w >> 2;
    for (int st = 0; st <= lastt; ++st) {
        // S = Q K^T
        f32x4 sa[4];
        #pragma unroll
        for (int ni = 0; ni < 4; ++ni) sa[ni] = (f32x4){0.f, 0.f, 0.f, 0.f};
        #pragma unroll
        for (int ni = 0; ni < 4; ++ni) {
            int row = st * 64 + ni * 16 + lr;
            #pragma unroll
            for (int kc = 0; kc < 2; ++kc) {
                bf16x8 kb = *(const bf16x8*)
                    &kl[row * 64 + ((kc * 32 + lk * 8) ^ ((lr & 7) << 3))];
                sa[ni] = __builtin_amdgcn_mfma_f32_16x16x32_bf16(qa[kc], kb, sa[ni], 0, 0, 0);
            }
        }
        // causal mask (diagonal tile only)
        if (st == lastt) {
            #pragma unroll
            for (int ni = 0; ni < 4; ++ni) {
                int sg = st * 64 + ni * 16 + lr;
                #pragma unroll
                for (int r = 0; r < 4; ++r) {
                    int qg = q0 + lk * 4 + r;
                    if (sg > qg) sa[ni][r] = -INFINITY;
                }
            }
        }
        // row max over ni, then over lr
        float pm[4];
        #pragma unroll
        for (int r = 0; r < 4; ++r)
            pm[r] = fmaxf(fmaxf(sa[0][r], sa[1][r]), fmaxf(sa[2][r], sa[3][r]));
        #pragma unroll
        for (int stp = 1; stp < 16; stp <<= 1)
            #pragma unroll
            for (int r = 0; r < 4; ++r)
                pm[r] = fmaxf(pm[r], __shfl_xor(pm[r], stp));
        // online update
        float mnew[4];
        #pragma unroll
        for (int r = 0; r < 4; ++r) {
            float mn = fmaxf(mrow[r], pm[r]);
            float corr = __expf(mrow[r] - mn);   // exp(-inf)=0 first time
            mrow[r] = mn; mnew[r] = mn;
            lpart[r] *= corr;
            #pragma unroll
            for (int nh = 0; nh < 4; ++nh) oacc[nh][r] *= corr;
        }
        // P = exp(S-m) -> wave-private swizzled LDS
        #pragma unroll
        for (int ni = 0; ni < 4; ++ni) {
            int s = ni * 16 + lr;
            #pragma unroll
            for (int r = 0; r < 4; ++r) {
                float p = __expf(sa[ni][r] - mnew[r]);
                lpart[r] += p;
                int qr = lk * 4 + r;
                pq[qr * 64 + (s ^ ((qr & 7) << 3))] = f2bf(p);
            }
        }
        // PV
        bf16x8 pa[2];
        #pragma unroll
        for (int kc = 0; kc < 2; ++kc)
            pa[kc] = *(const bf16x8*)
                &pq[lr * 64 + ((kc * 32 + lk * 8) ^ ((lr & 7) << 3))];
        #pragma unroll
        for (int nh = 0; nh < 4; ++nh) {
            int hrow = nh * 16 + lr;
            #pragma unroll
            for (int kc = 0; kc < 2; ++kc) {
                bf16x8 vb = *(const bf16x8*)
                    &vt[hrow * 256 + ((st * 64 + kc * 32 + lk * 8) ^ ((hrow & 7) << 3))];
                oacc[nh] = __builtin_amdgcn_mfma_f32_16x16x32_bf16(pa[kc], vb, oacc[nh], 0, 0, 0);
            }
        }
    }

    // ---- finalize ----
    float linv[4];
    #pragma unroll
    for (int r = 0; r < 4; ++r) {
        float l = lpart[r];
        #pragma unroll
        for (int stp = 1; stp < 16; stp <<= 1) l += __shfl_xor(l, stp);
        linv[r] = 1.0f / l;
    }
    #pragma unroll
    for (int nh = 0; nh < 4; ++nh)
        #pragma unroll
        for (int r = 0; r < 4; ++r) {
            size_t row = (size_t)b * TT + q0 + lk * 4 + r;
            out[row * HDIM + nh * 16 + lr] = oacc[nh][r] * linv[r];
        }
}

extern "C" void kernel_launch(void* const* d_in, const int* in_sizes, int n_in,
                              void* d_out, int out_size, void* d_ws, size_t ws_size,
                              hipStream_t stream)
{
    const float* x  = (const float*)d_in[0];
    const float* Wq = (const float*)d_in[1];
    const float* Wk = (const float*)d_in[2];
    const float* Wv = (const float*)d_in[3];
    unsigned short* bt = (unsigned short*)d_ws;   // [192][384] bf16 = 147 KB
    float* out = (float*)d_out;

    prep_bt<<<(NQKV * CDIM + 255) / 256, 256, 0, stream>>>(Wq, Wk, Wv, bt);
    fused<<<BSZ, 1024, 0, stream>>>(x, bt, out);
}